// Round 1
// baseline (2171.731 us; speedup 1.0000x reference)
//
#include <hip/hip_runtime.h>
#include <hip/hip_bf16.h>
#include <math.h>

#define B_  4
#define S_  2048
#define D_  1024
#define H_  16
#define DK_ 64
#define M_  (B_ * S_)   // 8192 rows

// ---------------------------------------------------------------------------
// GEMM: C = A @ W^T + bias.  A:[M_,D_] row-major, W:[D_,D_] row-major (torch
// Linear weight: [out,in]).  MODE 0: C row-major [M_,D_] (final output).
// MODE 1: scatter to [B,H,S,DK] layout for per-head attention access.
// 64x64 tile, BK=16, 256 threads, 4x4 micro-tile. k-major LDS (conflict-free).
// ---------------------------------------------------------------------------
template <int MODE>
__global__ __launch_bounds__(256) void gemm_nt_kernel(
    const float* __restrict__ A, const float* __restrict__ W,
    const float* __restrict__ bias, float* __restrict__ C)
{
    __shared__ float As[16][64];   // [k][m]
    __shared__ float Bs[16][64];   // [k][n]

    const int tid  = threadIdx.x;
    const int tm   = tid >> 4;          // 0..15
    const int tn   = tid & 15;          // 0..15
    const int m0   = blockIdx.x * 64;
    const int n0   = blockIdx.y * 64;
    const int lrow = tid >> 2;          // 0..63
    const int lcol = (tid & 3) << 2;    // 0,4,8,12

    const float* Ap = A + (size_t)(m0 + lrow) * D_ + lcol;
    const float* Wp = W + (size_t)(n0 + lrow) * D_ + lcol;

    float acc[4][4] = {};

    for (int k0 = 0; k0 < D_; k0 += 16) {
        float4 av = *(const float4*)(Ap + k0);
        float4 bv = *(const float4*)(Wp + k0);
        __syncthreads();   // previous iteration's LDS reads complete
        As[lcol + 0][lrow] = av.x; As[lcol + 1][lrow] = av.y;
        As[lcol + 2][lrow] = av.z; As[lcol + 3][lrow] = av.w;
        Bs[lcol + 0][lrow] = bv.x; Bs[lcol + 1][lrow] = bv.y;
        Bs[lcol + 2][lrow] = bv.z; Bs[lcol + 3][lrow] = bv.w;
        __syncthreads();
#pragma unroll
        for (int k = 0; k < 16; ++k) {
            float4 a4 = *(const float4*)&As[k][tm * 4];
            float4 b4 = *(const float4*)&Bs[k][tn * 4];
            float a[4] = {a4.x, a4.y, a4.z, a4.w};
            float b[4] = {b4.x, b4.y, b4.z, b4.w};
#pragma unroll
            for (int i = 0; i < 4; ++i)
#pragma unroll
                for (int j = 0; j < 4; ++j)
                    acc[i][j] = fmaf(a[i], b[j], acc[i][j]);
        }
    }

    const float4 bb = *(const float4*)(bias + n0 + tn * 4);
    const float bj[4] = {bb.x, bb.y, bb.z, bb.w};

#pragma unroll
    for (int i = 0; i < 4; ++i) {
        const int m = m0 + tm * 4 + i;
        float4 o;
        o.x = acc[i][0] + bj[0];
        o.y = acc[i][1] + bj[1];
        o.z = acc[i][2] + bj[2];
        o.w = acc[i][3] + bj[3];
        if (MODE == 0) {
            *(float4*)(C + (size_t)m * D_ + n0 + tn * 4) = o;
        } else {
            const int b = m >> 11;          // /S_
            const int s = m & (S_ - 1);
            const int n = n0 + tn * 4;
            const int h = n >> 6;
            const int d = n & 63;
            *(float4*)(C + ((size_t)(b * H_ + h) * S_ + s) * DK_ + d) = o;
        }
    }
}

// ---------------------------------------------------------------------------
// RoPE in-place on Q and K ([B*H, S, DK] layout). One wave per 64-dim row.
// out[d] = x[d]*cos(t*f[d&31]) + rot[d]*sin(t*f[d&31])
//   rot[d] = d<32 ? -x[2d+1] : x[2(d-32)]
// ---------------------------------------------------------------------------
__global__ __launch_bounds__(256) void rope_kernel(float* __restrict__ Q,
                                                   float* __restrict__ K)
{
    const int wave = blockIdx.x * 4 + (threadIdx.x >> 6);
    const int lane = threadIdx.x & 63;
    const int rowsPer = B_ * H_ * S_;   // 131072

    float* base = (wave < rowsPer) ? Q : K;
    const int row = (wave < rowsPer) ? wave : wave - rowsPer;
    const int s = row & (S_ - 1);

    float* p = base + (size_t)row * DK_;
    const float v = p[lane];

    const int j = lane & 31;
    const float inv_freq = 1.0f / powf(10000.0f, (float)(2 * j) / (float)DK_);
    const float ang = (float)s * inv_freq;
    const float c = cosf(ang);
    const float si = sinf(ang);

    const int partner = (lane < 32) ? (2 * lane + 1) : (2 * (lane - 32));
    const float sign = (lane < 32) ? -1.0f : 1.0f;
    const float pv = __shfl(v, partner);

    p[lane] = v * c + sign * pv * si;
}

// ---------------------------------------------------------------------------
// Causal flash attention, fp32. Block = (bh, 64-row Q tile), 256 threads.
// Q,K,V: [B*H, S, DK]. ctx written directly to [B,S,D] row-major.
// ---------------------------------------------------------------------------
__global__ __launch_bounds__(256) void attn_kernel(
    const float* __restrict__ Q, const float* __restrict__ K,
    const float* __restrict__ V, float* __restrict__ ctx)
{
    __shared__ float Qst[DK_][64 + 4];  // d-major, padded (aligned b128 reads)
    __shared__ float Kst[DK_][64 + 4];  // d-major
    __shared__ float Vs[64][DK_ + 4];   // natural [k][d]
    __shared__ float Ps[64][65];        // [k][q]

    const int tid = threadIdx.x;
    const int tm = tid >> 4, tn = tid & 15;
    const int bh = blockIdx.y;
    const int q0 = blockIdx.x * 64;
    const float scale = 0.125f;  // 1/sqrt(64)

    const float* Qp = Q + ((size_t)bh * S_ + q0) * DK_;
    const float* Kp = K + (size_t)bh * S_ * DK_;
    const float* Vp = V + (size_t)bh * S_ * DK_;

    // load Q tile (transposed to d-major)
    {
        const int r = tid >> 2;
        const int c = (tid & 3) * 16;
#pragma unroll
        for (int cc = 0; cc < 16; cc += 4) {
            float4 v4 = *(const float4*)(Qp + (size_t)r * DK_ + c + cc);
            Qst[c + cc + 0][r] = v4.x; Qst[c + cc + 1][r] = v4.y;
            Qst[c + cc + 2][r] = v4.z; Qst[c + cc + 3][r] = v4.w;
        }
    }

    float acc[4][4] = {};
    float m_i[4] = {-INFINITY, -INFINITY, -INFINITY, -INFINITY};
    float l_i[4] = {0.f, 0.f, 0.f, 0.f};

    for (int j0 = 0; j0 <= q0; j0 += 64) {
        __syncthreads();   // prior PV reads of Ks/Vs/Ps complete
        {
            const int r = tid >> 2;
            const int c = (tid & 3) * 16;
#pragma unroll
            for (int cc = 0; cc < 16; cc += 4) {
                float4 k4 = *(const float4*)(Kp + (size_t)(j0 + r) * DK_ + c + cc);
                Kst[c + cc + 0][r] = k4.x; Kst[c + cc + 1][r] = k4.y;
                Kst[c + cc + 2][r] = k4.z; Kst[c + cc + 3][r] = k4.w;
                float4 v4 = *(const float4*)(Vp + (size_t)(j0 + r) * DK_ + c + cc);
                *(float4*)&Vs[r][c + cc] = v4;
            }
        }
        __syncthreads();

        // scores: sc[i][j] = Q[q0+tm*4+i] . K[j0+tn*4+j]
        float sc[4][4] = {};
#pragma unroll 16
        for (int d = 0; d < DK_; ++d) {
            float4 q4 = *(const float4*)&Qst[d][tm * 4];
            float4 k4 = *(const float4*)&Kst[d][tn * 4];
            float a[4] = {q4.x, q4.y, q4.z, q4.w};
            float b[4] = {k4.x, k4.y, k4.z, k4.w};
#pragma unroll
            for (int i = 0; i < 4; ++i)
#pragma unroll
                for (int j = 0; j < 4; ++j)
                    sc[i][j] = fmaf(a[i], b[j], sc[i][j]);
        }

        const bool diag = (j0 == q0);
#pragma unroll
        for (int i = 0; i < 4; ++i) {
            const int qrow = q0 + tm * 4 + i;
            float rmax = -1e30f;
#pragma unroll
            for (int j = 0; j < 4; ++j) {
                float s = sc[i][j] * scale;
                if (diag && (j0 + tn * 4 + j > qrow)) s = -1e9f;
                sc[i][j] = s;
                rmax = fmaxf(rmax, s);
            }
            rmax = fmaxf(rmax, __shfl_xor(rmax, 1));
            rmax = fmaxf(rmax, __shfl_xor(rmax, 2));
            rmax = fmaxf(rmax, __shfl_xor(rmax, 4));
            rmax = fmaxf(rmax, __shfl_xor(rmax, 8));

            const float mnew = fmaxf(m_i[i], rmax);
            const float alpha = __expf(m_i[i] - mnew);
            float rsum = 0.f;
#pragma unroll
            for (int j = 0; j < 4; ++j) {
                const float p = __expf(sc[i][j] - mnew);
                sc[i][j] = p;
                rsum += p;
            }
            rsum += __shfl_xor(rsum, 1);
            rsum += __shfl_xor(rsum, 2);
            rsum += __shfl_xor(rsum, 4);
            rsum += __shfl_xor(rsum, 8);

            l_i[i] = l_i[i] * alpha + rsum;
            m_i[i] = mnew;
#pragma unroll
            for (int j = 0; j < 4; ++j) acc[i][j] *= alpha;

            // stash P transposed: Ps[k][q]
#pragma unroll
            for (int j = 0; j < 4; ++j)
                Ps[tn * 4 + j][tm * 4 + i] = sc[i][j];
        }
        __syncthreads();

        // acc[i][j] += sum_k P[q][k] * V[k][d],  d = tn*4+j
#pragma unroll 8
        for (int k = 0; k < 64; ++k) {
            float4 v4 = *(const float4*)&Vs[k][tn * 4];
            float vb[4] = {v4.x, v4.y, v4.z, v4.w};
            float pk[4];
#pragma unroll
            for (int i = 0; i < 4; ++i) pk[i] = Ps[k][tm * 4 + i];
#pragma unroll
            for (int i = 0; i < 4; ++i)
#pragma unroll
                for (int j = 0; j < 4; ++j)
                    acc[i][j] = fmaf(pk[i], vb[j], acc[i][j]);
        }
    }

    // epilogue: normalize and write ctx in [B,S,D] layout
    const int b = bh >> 4, h = bh & 15;
#pragma unroll
    for (int i = 0; i < 4; ++i) {
        const float inv = 1.0f / l_i[i];
        const int srow = q0 + tm * 4 + i;
        float4 o;
        o.x = acc[i][0] * inv;
        o.y = acc[i][1] * inv;
        o.z = acc[i][2] * inv;
        o.w = acc[i][3] * inv;
        *(float4*)(ctx + (size_t)(b * S_ + srow) * D_ + h * DK_ + tn * 4) = o;
    }
}

// ---------------------------------------------------------------------------
extern "C" void kernel_launch(void* const* d_in, const int* in_sizes, int n_in,
                              void* d_out, int out_size, void* d_ws, size_t ws_size,
                              hipStream_t stream)
{
    const float* query = (const float*)d_in[0];
    const float* key   = (const float*)d_in[1];
    const float* value = (const float*)d_in[2];
    // d_in[3] = mask (causal tril) — hardcoded in attn_kernel
    const float* w_q = (const float*)d_in[4];
    const float* b_q = (const float*)d_in[5];
    const float* w_k = (const float*)d_in[6];
    const float* b_k = (const float*)d_in[7];
    const float* w_v = (const float*)d_in[8];
    const float* b_v = (const float*)d_in[9];
    const float* w_o = (const float*)d_in[10];
    const float* b_o = (const float*)d_in[11];
    float* out = (float*)d_out;

    char* ws = (char*)d_ws;
    const size_t tb = (size_t)M_ * D_ * sizeof(float);   // 33.55 MB
    float* Qb = (float*)(ws);
    float* Kb = (float*)(ws + tb);
    float* Vb = (float*)(ws + 2 * tb);
    float* Cb = (float*)(ws + 3 * tb);

    dim3 gg(M_ / 64, D_ / 64);   // 128 x 16
    gemm_nt_kernel<1><<<gg, 256, 0, stream>>>(query, w_q, b_q, Qb);
    gemm_nt_kernel<1><<<gg, 256, 0, stream>>>(key,   w_k, b_k, Kb);
    gemm_nt_kernel<1><<<gg, 256, 0, stream>>>(value, w_v, b_v, Vb);

    rope_kernel<<<(2 * B_ * H_ * S_) / 4, 256, 0, stream>>>(Qb, Kb);

    attn_kernel<<<dim3(S_ / 64, B_ * H_), 256, 0, stream>>>(Qb, Kb, Vb, Cb);

    gemm_nt_kernel<0><<<gg, 256, 0, stream>>>(Cb, w_o, b_o, out);
}

// Round 2
// 1419.725 us; speedup vs baseline: 1.5297x; 1.5297x over previous
//
#include <hip/hip_runtime.h>
#include <hip/hip_bf16.h>
#include <math.h>

#define B_  4
#define S_  2048
#define D_  1024
#define H_  16
#define DK_ 64
#define M_  (B_ * S_)   // 8192 rows

typedef short short8 __attribute__((ext_vector_type(8)));
typedef float floatx4 __attribute__((ext_vector_type(4)));

__device__ inline unsigned short f2bf(float x) {
    unsigned u = __float_as_uint(x);
    u = (u + 0x7fff + ((u >> 16) & 1)) >> 16;   // round-to-nearest-even
    return (unsigned short)u;
}
__device__ inline float bf2f(unsigned short h) {
    return __uint_as_float(((unsigned)h) << 16);
}

// ---------------------------------------------------------------------------
// GEMM: C = A @ W^T + bias.  A:[M_,D_] rm, W:[D_,D_] rm (torch Linear).
// MODE 0: fp32 row-major [M_,D_].  MODE 1: fp32 scatter [B,H,S,DK].
// MODE 2: bf16 scatter [B,H,S,DK] (compact, stride 64).
// ---------------------------------------------------------------------------
template <int MODE>
__global__ __launch_bounds__(256) void gemm_nt_kernel(
    const float* __restrict__ A, const float* __restrict__ W,
    const float* __restrict__ bias, void* __restrict__ Cv)
{
    __shared__ float As[16][64];
    __shared__ float Bs[16][64];

    const int tid  = threadIdx.x;
    const int tm   = tid >> 4;
    const int tn   = tid & 15;
    const int m0   = blockIdx.x * 64;
    const int n0   = blockIdx.y * 64;
    const int lrow = tid >> 2;
    const int lcol = (tid & 3) << 2;

    const float* Ap = A + (size_t)(m0 + lrow) * D_ + lcol;
    const float* Wp = W + (size_t)(n0 + lrow) * D_ + lcol;

    float acc[4][4] = {};

    for (int k0 = 0; k0 < D_; k0 += 16) {
        float4 av = *(const float4*)(Ap + k0);
        float4 bv = *(const float4*)(Wp + k0);
        __syncthreads();
        As[lcol + 0][lrow] = av.x; As[lcol + 1][lrow] = av.y;
        As[lcol + 2][lrow] = av.z; As[lcol + 3][lrow] = av.w;
        Bs[lcol + 0][lrow] = bv.x; Bs[lcol + 1][lrow] = bv.y;
        Bs[lcol + 2][lrow] = bv.z; Bs[lcol + 3][lrow] = bv.w;
        __syncthreads();
#pragma unroll
        for (int k = 0; k < 16; ++k) {
            float4 a4 = *(const float4*)&As[k][tm * 4];
            float4 b4 = *(const float4*)&Bs[k][tn * 4];
            float a[4] = {a4.x, a4.y, a4.z, a4.w};
            float b[4] = {b4.x, b4.y, b4.z, b4.w};
#pragma unroll
            for (int i = 0; i < 4; ++i)
#pragma unroll
                for (int j = 0; j < 4; ++j)
                    acc[i][j] = fmaf(a[i], b[j], acc[i][j]);
        }
    }

    const float4 bb = *(const float4*)(bias + n0 + tn * 4);
    const float bj[4] = {bb.x, bb.y, bb.z, bb.w};

#pragma unroll
    for (int i = 0; i < 4; ++i) {
        const int m = m0 + tm * 4 + i;
        float o[4];
#pragma unroll
        for (int j = 0; j < 4; ++j) o[j] = acc[i][j] + bj[j];

        if (MODE == 0) {
            float* C = (float*)Cv;
            *(float4*)(C + (size_t)m * D_ + n0 + tn * 4) =
                make_float4(o[0], o[1], o[2], o[3]);
        } else {
            const int b = m >> 11;
            const int s = m & (S_ - 1);
            const int n = n0 + tn * 4;
            const int h = n >> 6;
            const int d = n & 63;
            if (MODE == 1) {
                float* C = (float*)Cv;
                *(float4*)(C + ((size_t)(b * H_ + h) * S_ + s) * DK_ + d) =
                    make_float4(o[0], o[1], o[2], o[3]);
            } else {
                unsigned short* C = (unsigned short*)Cv;
                ushort4 o16;
                o16.x = f2bf(o[0]); o16.y = f2bf(o[1]);
                o16.z = f2bf(o[2]); o16.w = f2bf(o[3]);
                *(ushort4*)(C + ((size_t)(b * H_ + h) * S_ + s) * DK_ + d) = o16;
            }
        }
    }
}

// ---------------------------------------------------------------------------
// RoPE: read fp32 row [B*H,S,DK], write bf16 IN PLACE (row stride becomes
// 128 bf16 elements over the same storage; data in first 64).
// ---------------------------------------------------------------------------
__global__ __launch_bounds__(256) void rope_kernel(float* __restrict__ Q,
                                                   float* __restrict__ K)
{
    const int wave = blockIdx.x * 4 + (threadIdx.x >> 6);
    const int lane = threadIdx.x & 63;
    const int rowsPer = B_ * H_ * S_;

    float* base = (wave < rowsPer) ? Q : K;
    const int row = (wave < rowsPer) ? wave : wave - rowsPer;
    const int s = row & (S_ - 1);

    float* p = base + (size_t)row * DK_;
    const float v = p[lane];

    const int j = lane & 31;
    const float inv_freq = 1.0f / powf(10000.0f, (float)(2 * j) / (float)DK_);
    const float ang = (float)s * inv_freq;
    const float c  = cosf(ang);
    const float si = sinf(ang);

    const int partner = (lane < 32) ? (2 * lane + 1) : (2 * (lane - 32));
    const float sign = (lane < 32) ? -1.0f : 1.0f;
    const float pv = __shfl(v, partner);

    const float val = v * c + sign * pv * si;
    ((unsigned short*)p)[lane] = f2bf(val);
}

// ---------------------------------------------------------------------------
// MFMA flash attention (bf16 inputs, fp32 accum).
// Block: 256 thr = 4 waves; 64 Q rows (16/wave), Bc = 64.
// Qh,Kh: bf16, row stride 128 (in-place over fp32 storage). Vh: bf16 stride 64.
// C/D layout: col = lane&15, row = (lane>>4)*4 + reg.
// A layout:   m = lane&15, k = (lane>>4)*8 + j (+32 for second frag).
// ---------------------------------------------------------------------------
#define KSTR 72   // padded LDS row stride (bf16 elems), 144 B = 16B-aligned

__global__ __launch_bounds__(256) void attn_kernel(
    const unsigned short* __restrict__ Qh, const unsigned short* __restrict__ Kh,
    const unsigned short* __restrict__ Vh, float* __restrict__ ctx)
{
    __shared__ __align__(16) short Ks[64 * KSTR];       // [kv][d]
    __shared__ __align__(16) short Vt[64 * KSTR];       // [d][kv]
    __shared__ __align__(16) short Pw[4 * 16 * KSTR];   // per-wave [q][kv]

    const int tid  = threadIdx.x;
    const int wave = tid >> 6;
    const int lane = tid & 63;
    const int quad = lane >> 4;
    const int l15  = lane & 15;
    const int bh   = blockIdx.y;
    const int q0   = blockIdx.x * 64;
    const float scale = 0.125f;

    // ---- Q fragments (held in registers for whole kernel) ----
    const unsigned short* Qrow =
        Qh + ((size_t)bh * S_ + q0 + wave * 16 + l15) * 128;
    short8 aQ[2];
    aQ[0] = *(const short8*)(Qrow + quad * 8);
    aQ[1] = *(const short8*)(Qrow + 32 + quad * 8);

    floatx4 acc[4] = {};
    float m_i[4] = {-INFINITY, -INFINITY, -INFINITY, -INFINITY};
    float l_i[4] = {0.f, 0.f, 0.f, 0.f};

    const unsigned short* Kbase = Kh + (size_t)bh * S_ * 128;
    const unsigned short* Vbase = Vh + (size_t)bh * S_ * DK_;

    for (int j0 = 0; j0 <= q0; j0 += 64) {
        __syncthreads();   // prior PV reads of Ks/Vt complete

        // ---- stage K natural [kv][d] ----
        {
            const int r = tid >> 2;
            const int cg = (tid & 3) * 16;
#pragma unroll
            for (int h = 0; h < 2; ++h) {
                const int c = cg + h * 8;
                short8 kv8 = *(const short8*)(Kbase + (size_t)(j0 + r) * 128 + c);
                *(short8*)&Ks[r * KSTR + c] = kv8;
            }
        }
        // ---- stage V transposed [d][kv] ----
        {
            const int r = lane;
#pragma unroll
            for (int h = 0; h < 2; ++h) {
                const int c = h * 32 + wave * 8;
                short8 v8 = *(const short8*)(Vbase + (size_t)(j0 + r) * DK_ + c);
#pragma unroll
                for (int i = 0; i < 8; ++i)
                    Vt[(c + i) * KSTR + r] = v8[i];
            }
        }
        __syncthreads();

        // ---- scores: 16x64 strip per wave ----
        floatx4 st[4] = {};
#pragma unroll
        for (int t = 0; t < 4; ++t) {
#pragma unroll
            for (int kh = 0; kh < 2; ++kh) {
                short8 bK = *(const short8*)&Ks[(t * 16 + l15) * KSTR + kh * 32 + quad * 8];
                st[t] = __builtin_amdgcn_mfma_f32_16x16x32_bf16(aQ[kh], bK, st[t], 0, 0, 0);
            }
        }

        // ---- online softmax ----
        const bool diag = (j0 == q0);
        float s[4][4];   // [t][reg]
#pragma unroll
        for (int t = 0; t < 4; ++t)
#pragma unroll
            for (int reg = 0; reg < 4; ++reg) {
                float v = st[t][reg] * scale;
                if (diag && (t * 16 + l15 > wave * 16 + quad * 4 + reg))
                    v = -INFINITY;
                s[t][reg] = v;
            }

#pragma unroll
        for (int reg = 0; reg < 4; ++reg) {
            float rmax = fmaxf(fmaxf(s[0][reg], s[1][reg]),
                               fmaxf(s[2][reg], s[3][reg]));
            rmax = fmaxf(rmax, __shfl_xor(rmax, 1));
            rmax = fmaxf(rmax, __shfl_xor(rmax, 2));
            rmax = fmaxf(rmax, __shfl_xor(rmax, 4));
            rmax = fmaxf(rmax, __shfl_xor(rmax, 8));

            const float mn = fmaxf(m_i[reg], rmax);
            const float alpha = __expf(m_i[reg] - mn);
            float rs = 0.f;
#pragma unroll
            for (int t = 0; t < 4; ++t) {
                const unsigned short pb = f2bf(__expf(s[t][reg] - mn));
                Pw[(wave * 16 + quad * 4 + reg) * KSTR + t * 16 + l15] = pb;
                rs += bf2f(pb);   // l matches bf16 P exactly
            }
            rs += __shfl_xor(rs, 1);
            rs += __shfl_xor(rs, 2);
            rs += __shfl_xor(rs, 4);
            rs += __shfl_xor(rs, 8);

            l_i[reg] = l_i[reg] * alpha + rs;
            m_i[reg] = mn;
#pragma unroll
            for (int t = 0; t < 4; ++t) acc[t][reg] *= alpha;
        }

        // ---- PV: acc[16x64] += P[16x64] @ V[64x64] ----
#pragma unroll
        for (int kh = 0; kh < 2; ++kh) {
            short8 aP = *(const short8*)&Pw[(wave * 16 + l15) * KSTR + kh * 32 + quad * 8];
#pragma unroll
            for (int t = 0; t < 4; ++t) {
                short8 bV = *(const short8*)&Vt[(t * 16 + l15) * KSTR + kh * 32 + quad * 8];
                acc[t] = __builtin_amdgcn_mfma_f32_16x16x32_bf16(aP, bV, acc[t], 0, 0, 0);
            }
        }
    }

    // ---- epilogue: normalize, write ctx [B,S,D] ----
    const int b = bh >> 4, h = bh & 15;
#pragma unroll
    for (int reg = 0; reg < 4; ++reg) {
        const float inv = 1.0f / l_i[reg];
        const int q = q0 + wave * 16 + quad * 4 + reg;
        float* orow = ctx + ((size_t)b * S_ + q) * D_ + h * DK_;
#pragma unroll
        for (int t = 0; t < 4; ++t)
            orow[t * 16 + l15] = acc[t][reg] * inv;
    }
}

// ---------------------------------------------------------------------------
extern "C" void kernel_launch(void* const* d_in, const int* in_sizes, int n_in,
                              void* d_out, int out_size, void* d_ws, size_t ws_size,
                              hipStream_t stream)
{
    const float* query = (const float*)d_in[0];
    const float* key   = (const float*)d_in[1];
    const float* value = (const float*)d_in[2];
    const float* w_q = (const float*)d_in[4];
    const float* b_q = (const float*)d_in[5];
    const float* w_k = (const float*)d_in[6];
    const float* b_k = (const float*)d_in[7];
    const float* w_v = (const float*)d_in[8];
    const float* b_v = (const float*)d_in[9];
    const float* w_o = (const float*)d_in[10];
    const float* b_o = (const float*)d_in[11];
    float* out = (float*)d_out;

    char* ws = (char*)d_ws;
    const size_t tb = (size_t)M_ * D_ * sizeof(float);   // 33.55 MB
    float*          Qb = (float*)(ws);                    // fp32 -> bf16 in place
    float*          Kb = (float*)(ws + tb);               // fp32 -> bf16 in place
    unsigned short* Vh = (unsigned short*)(ws + 2 * tb);  // bf16 compact
    float*          Cb = (float*)(ws + 2 * tb + tb / 2);  // ctx fp32

    dim3 gg(M_ / 64, D_ / 64);
    gemm_nt_kernel<1><<<gg, 256, 0, stream>>>(query, w_q, b_q, Qb);
    gemm_nt_kernel<1><<<gg, 256, 0, stream>>>(key,   w_k, b_k, Kb);
    gemm_nt_kernel<2><<<gg, 256, 0, stream>>>(value, w_v, b_v, Vh);

    rope_kernel<<<(2 * B_ * H_ * S_) / 4, 256, 0, stream>>>(Qb, Kb);

    attn_kernel<<<dim3(S_ / 64, B_ * H_), 256, 0, stream>>>(
        (const unsigned short*)Qb, (const unsigned short*)Kb, Vh, Cb);

    gemm_nt_kernel<0><<<gg, 256, 0, stream>>>(Cb, w_o, b_o, out);
}

// Round 3
// 600.737 us; speedup vs baseline: 3.6151x; 2.3633x over previous
//
#include <hip/hip_runtime.h>
#include <hip/hip_bf16.h>
#include <math.h>

#define B_  4
#define S_  2048
#define D_  1024
#define H_  16
#define DK_ 64
#define M_  (B_ * S_)   // 8192 rows

typedef short short8 __attribute__((ext_vector_type(8)));
typedef float floatx4 __attribute__((ext_vector_type(4)));

__device__ inline unsigned short f2bf(float x) {
    unsigned u = __float_as_uint(x);
    u = (u + 0x7fff + ((u >> 16) & 1)) >> 16;   // round-to-nearest-even
    return (unsigned short)u;
}
__device__ inline float bf2f(unsigned short h) {
    return __uint_as_float(((unsigned)h) << 16);
}

#define GLOAD_LDS16(g, l)                                          \
    __builtin_amdgcn_global_load_lds(                              \
        (const __attribute__((address_space(1))) void*)(g),        \
        (__attribute__((address_space(3))) void*)(l), 16, 0, 0)

// ---------------------------------------------------------------------------
// fp32 -> bf16 converters
// ---------------------------------------------------------------------------
__global__ __launch_bounds__(256) void cvt_inputs_kernel(
    const float* __restrict__ q, const float* __restrict__ k,
    const float* __restrict__ v, unsigned short* __restrict__ Ah)
{
    const int z = blockIdx.z;
    const float* src = (z == 0) ? q : (z == 1) ? k : v;
    unsigned short* dst = Ah + (size_t)z * M_ * D_;
    const size_t i = ((size_t)blockIdx.x * 256 + threadIdx.x) * 4;
    float4 f = *(const float4*)(src + i);
    ushort4 o;
    o.x = f2bf(f.x); o.y = f2bf(f.y); o.z = f2bf(f.z); o.w = f2bf(f.w);
    *(ushort4*)(dst + i) = o;
}

__global__ __launch_bounds__(256) void cvt_weights_kernel(
    const float* __restrict__ wq, const float* __restrict__ wk,
    const float* __restrict__ wv, const float* __restrict__ wo,
    unsigned short* __restrict__ Wh, unsigned short* __restrict__ Woh)
{
    const int z = blockIdx.z;
    const float* src = (z == 0) ? wq : (z == 1) ? wk : (z == 2) ? wv : wo;
    unsigned short* dst = (z < 3) ? (Wh + (size_t)z * D_ * D_) : Woh;
    const size_t i = ((size_t)blockIdx.x * 256 + threadIdx.x) * 4;
    float4 f = *(const float4*)(src + i);
    ushort4 o;
    o.x = f2bf(f.x); o.y = f2bf(f.y); o.z = f2bf(f.z); o.w = f2bf(f.w);
    *(ushort4*)(dst + i) = o;
}

// ---------------------------------------------------------------------------
// bf16 MFMA NT-GEMM (m97 structure): C = A @ W^T + bias.
// A:[M_,K=1024] bf16 rm, W:[1024,1024] bf16 rm ([out,in]).
// 128x128 tile, BK=32, 256 thr = 4 waves (2x2 of 64x64), 4x4 16x16x32 frags.
// MODE 0: fp32 row-major out (O-proj), single z.
// MODE 1: bf16 scatter [B,H,S,DK], z = 0/1/2 selects Q/K/V.
// ---------------------------------------------------------------------------
template <int MODE>
__global__ __launch_bounds__(256) void gemm_bf16_kernel(
    const unsigned short* __restrict__ Ah, const unsigned short* __restrict__ Wh,
    const float* __restrict__ bq, const float* __restrict__ bk,
    const float* __restrict__ bv, void* __restrict__ outv)
{
    __shared__ __align__(16) unsigned short As[128 * 32];   // [m][k]
    __shared__ __align__(16) unsigned short Bs[128 * 32];   // [n][k]

    const int tid  = threadIdx.x;
    const int wave = tid >> 6;
    const int lane = tid & 63;
    const int quad = lane >> 4;
    const int l15  = lane & 15;
    const int z    = (MODE == 1) ? blockIdx.z : 0;
    const int m0   = blockIdx.x * 128;
    const int n0   = blockIdx.y * 128;
    const int wrow = (wave >> 1) * 64;
    const int wcol = (wave & 1) * 64;

    const unsigned short* A = Ah + (size_t)z * M_ * D_;
    const unsigned short* W = Wh + (size_t)z * D_ * D_;

    const int srow   = tid >> 2;         // 0..63
    const int schunk = (tid & 3) * 8;    // k-offset in elems

    floatx4 acc[4][4] = {};

    for (int k0 = 0; k0 < D_; k0 += 32) {
        __syncthreads();   // prior frag reads done before overwrite
#pragma unroll
        for (int p = 0; p < 2; ++p) {
            const unsigned short* ga =
                A + (size_t)(m0 + p * 64 + srow) * D_ + k0 + schunk;
            GLOAD_LDS16(ga, &As[p * 2048 + wave * 512]);
            const unsigned short* gb =
                W + (size_t)(n0 + p * 64 + srow) * D_ + k0 + schunk;
            GLOAD_LDS16(gb, &Bs[p * 2048 + wave * 512]);
        }
        __syncthreads();   // staging visible (compiler drains vmcnt)

        short8 af[4], bf[4];
#pragma unroll
        for (int i = 0; i < 4; ++i)
            af[i] = *(const short8*)&As[(wrow + i * 16 + l15) * 32 + quad * 8];
#pragma unroll
        for (int j = 0; j < 4; ++j)
            bf[j] = *(const short8*)&Bs[(wcol + j * 16 + l15) * 32 + quad * 8];
#pragma unroll
        for (int i = 0; i < 4; ++i)
#pragma unroll
            for (int j = 0; j < 4; ++j)
                acc[i][j] = __builtin_amdgcn_mfma_f32_16x16x32_bf16(
                    af[i], bf[j], acc[i][j], 0, 0, 0);
    }

    const float* bias = (MODE == 0) ? bq : (z == 0) ? bq : (z == 1) ? bk : bv;

#pragma unroll
    for (int j = 0; j < 4; ++j) {
        const int n = n0 + wcol + j * 16 + l15;
        const float bn = bias[n];
#pragma unroll
        for (int i = 0; i < 4; ++i) {
#pragma unroll
            for (int reg = 0; reg < 4; ++reg) {
                const int m = m0 + wrow + i * 16 + quad * 4 + reg;
                const float v = acc[i][j][reg] + bn;
                if (MODE == 0) {
                    ((float*)outv)[(size_t)m * D_ + n] = v;
                } else {
                    const int b = m >> 11;
                    const int s = m & (S_ - 1);
                    const int h = n >> 6;
                    const int d = n & 63;
                    unsigned short* dst =
                        (unsigned short*)outv + (size_t)z * M_ * D_;
                    dst[(((size_t)b * H_ + h) * S_ + s) * DK_ + d] = f2bf(v);
                }
            }
        }
    }
}

// ---------------------------------------------------------------------------
// RoPE in-place on bf16 Q and K ([B*H, S, DK] compact). One wave per row.
// ---------------------------------------------------------------------------
__global__ __launch_bounds__(256) void rope_kernel(unsigned short* __restrict__ Q,
                                                   unsigned short* __restrict__ K)
{
    const int wave = blockIdx.x * 4 + (threadIdx.x >> 6);
    const int lane = threadIdx.x & 63;
    const int rowsPer = B_ * H_ * S_;

    unsigned short* base = (wave < rowsPer) ? Q : K;
    const int row = (wave < rowsPer) ? wave : wave - rowsPer;
    const int s = row & (S_ - 1);

    unsigned short* p = base + (size_t)row * DK_;
    const float v = bf2f(p[lane]);

    const int j = lane & 31;
    const float inv_freq = 1.0f / powf(10000.0f, (float)(2 * j) / (float)DK_);
    const float ang = (float)s * inv_freq;
    const float c  = cosf(ang);
    const float si = sinf(ang);

    const int partner = (lane < 32) ? (2 * lane + 1) : (2 * (lane - 32));
    const float sign = (lane < 32) ? -1.0f : 1.0f;
    const float pv = __shfl(v, partner);

    p[lane] = f2bf(v * c + sign * pv * si);
}

// ---------------------------------------------------------------------------
// MFMA flash attention (bf16 in, fp32 accum). Block = 4 waves, 64 Q rows.
// Qh,Kh,Vh: bf16 compact [B*H, S, DK]. ctx out: bf16 [M_, D_] row-major.
// ---------------------------------------------------------------------------
#define KSTR 72

__global__ __launch_bounds__(256) void attn_kernel(
    const unsigned short* __restrict__ Qh, const unsigned short* __restrict__ Kh,
    const unsigned short* __restrict__ Vh, unsigned short* __restrict__ ctx)
{
    __shared__ __align__(16) short Ks[64 * KSTR];       // [kv][d]
    __shared__ __align__(16) short Vt[64 * KSTR];       // [d][kv]
    __shared__ __align__(16) short Pw[4 * 16 * KSTR];   // per-wave [q][kv]

    const int tid  = threadIdx.x;
    const int wave = tid >> 6;
    const int lane = tid & 63;
    const int quad = lane >> 4;
    const int l15  = lane & 15;
    const int bh   = blockIdx.y;
    const int q0   = blockIdx.x * 64;
    const float scale = 0.125f;

    const unsigned short* Qrow =
        Qh + ((size_t)bh * S_ + q0 + wave * 16 + l15) * DK_;
    short8 aQ[2];
    aQ[0] = *(const short8*)(Qrow + quad * 8);
    aQ[1] = *(const short8*)(Qrow + 32 + quad * 8);

    floatx4 acc[4] = {};
    float m_i[4] = {-INFINITY, -INFINITY, -INFINITY, -INFINITY};
    float l_i[4] = {0.f, 0.f, 0.f, 0.f};

    const unsigned short* Kbase = Kh + (size_t)bh * S_ * DK_;
    const unsigned short* Vbase = Vh + (size_t)bh * S_ * DK_;

    for (int j0 = 0; j0 <= q0; j0 += 64) {
        __syncthreads();

        {   // stage K natural [kv][d]
            const int r = tid >> 2;
            const int cg = (tid & 3) * 16;
#pragma unroll
            for (int h = 0; h < 2; ++h) {
                const int c = cg + h * 8;
                short8 kv8 = *(const short8*)(Kbase + (size_t)(j0 + r) * DK_ + c);
                *(short8*)&Ks[r * KSTR + c] = kv8;
            }
        }
        {   // stage V transposed [d][kv]
            const int r = lane;
#pragma unroll
            for (int h = 0; h < 2; ++h) {
                const int c = h * 32 + wave * 8;
                short8 v8 = *(const short8*)(Vbase + (size_t)(j0 + r) * DK_ + c);
#pragma unroll
                for (int i = 0; i < 8; ++i)
                    Vt[(c + i) * KSTR + r] = v8[i];
            }
        }
        __syncthreads();

        floatx4 st[4] = {};
#pragma unroll
        for (int t = 0; t < 4; ++t) {
#pragma unroll
            for (int kh = 0; kh < 2; ++kh) {
                short8 bK = *(const short8*)&Ks[(t * 16 + l15) * KSTR + kh * 32 + quad * 8];
                st[t] = __builtin_amdgcn_mfma_f32_16x16x32_bf16(aQ[kh], bK, st[t], 0, 0, 0);
            }
        }

        const bool diag = (j0 == q0);
        float s[4][4];
#pragma unroll
        for (int t = 0; t < 4; ++t)
#pragma unroll
            for (int reg = 0; reg < 4; ++reg) {
                float v = st[t][reg] * scale;
                if (diag && (t * 16 + l15 > wave * 16 + quad * 4 + reg))
                    v = -INFINITY;
                s[t][reg] = v;
            }

#pragma unroll
        for (int reg = 0; reg < 4; ++reg) {
            float rmax = fmaxf(fmaxf(s[0][reg], s[1][reg]),
                               fmaxf(s[2][reg], s[3][reg]));
            rmax = fmaxf(rmax, __shfl_xor(rmax, 1));
            rmax = fmaxf(rmax, __shfl_xor(rmax, 2));
            rmax = fmaxf(rmax, __shfl_xor(rmax, 4));
            rmax = fmaxf(rmax, __shfl_xor(rmax, 8));

            const float mn = fmaxf(m_i[reg], rmax);
            const float alpha = __expf(m_i[reg] - mn);
            float rs = 0.f;
#pragma unroll
            for (int t = 0; t < 4; ++t) {
                const unsigned short pb = f2bf(__expf(s[t][reg] - mn));
                Pw[(wave * 16 + quad * 4 + reg) * KSTR + t * 16 + l15] = pb;
                rs += bf2f(pb);
            }
            rs += __shfl_xor(rs, 1);
            rs += __shfl_xor(rs, 2);
            rs += __shfl_xor(rs, 4);
            rs += __shfl_xor(rs, 8);

            l_i[reg] = l_i[reg] * alpha + rs;
            m_i[reg] = mn;
#pragma unroll
            for (int t = 0; t < 4; ++t) acc[t][reg] *= alpha;
        }

#pragma unroll
        for (int kh = 0; kh < 2; ++kh) {
            short8 aP = *(const short8*)&Pw[(wave * 16 + l15) * KSTR + kh * 32 + quad * 8];
#pragma unroll
            for (int t = 0; t < 4; ++t) {
                short8 bV = *(const short8*)&Vt[(t * 16 + l15) * KSTR + kh * 32 + quad * 8];
                acc[t] = __builtin_amdgcn_mfma_f32_16x16x32_bf16(aP, bV, acc[t], 0, 0, 0);
            }
        }
    }

    const int b = bh >> 4, h = bh & 15;
#pragma unroll
    for (int reg = 0; reg < 4; ++reg) {
        const float inv = 1.0f / l_i[reg];
        const int q = q0 + wave * 16 + quad * 4 + reg;
        unsigned short* orow = ctx + ((size_t)b * S_ + q) * D_ + h * DK_;
#pragma unroll
        for (int t = 0; t < 4; ++t)
            orow[t * 16 + l15] = f2bf(acc[t][reg] * inv);
    }
}

// ---------------------------------------------------------------------------
extern "C" void kernel_launch(void* const* d_in, const int* in_sizes, int n_in,
                              void* d_out, int out_size, void* d_ws, size_t ws_size,
                              hipStream_t stream)
{
    const float* query = (const float*)d_in[0];
    const float* key   = (const float*)d_in[1];
    const float* value = (const float*)d_in[2];
    const float* w_q = (const float*)d_in[4];
    const float* b_q = (const float*)d_in[5];
    const float* w_k = (const float*)d_in[6];
    const float* b_k = (const float*)d_in[7];
    const float* w_v = (const float*)d_in[8];
    const float* b_v = (const float*)d_in[9];
    const float* w_o = (const float*)d_in[10];
    const float* b_o = (const float*)d_in[11];
    float* out = (float*)d_out;

    char* ws = (char*)d_ws;
    const size_t half = (size_t)M_ * D_ * sizeof(unsigned short);   // 16.78 MB
    unsigned short* Ah   = (unsigned short*)(ws);                    // [3][M,D] bf16
    unsigned short* Wh   = (unsigned short*)(ws + 3 * half);         // [3][D,D]
    unsigned short* Woh  = (unsigned short*)(ws + 3 * half + 3 * half / 8);
    unsigned short* QKVb = (unsigned short*)(ws + 3 * half + 4 * half / 8);
    unsigned short* Ctxh = (unsigned short*)(ws + 6 * half + 4 * half / 8);

    cvt_inputs_kernel<<<dim3(M_ * D_ / 1024, 1, 3), 256, 0, stream>>>(
        query, key, value, Ah);
    cvt_weights_kernel<<<dim3(D_ * D_ / 1024, 1, 4), 256, 0, stream>>>(
        w_q, w_k, w_v, w_o, Wh, Woh);

    gemm_bf16_kernel<1><<<dim3(M_ / 128, D_ / 128, 3), 256, 0, stream>>>(
        Ah, Wh, b_q, b_k, b_v, QKVb);

    unsigned short* Qb = QKVb;
    unsigned short* Kb = QKVb + (size_t)M_ * D_;
    unsigned short* Vb = QKVb + 2 * (size_t)M_ * D_;

    rope_kernel<<<(2 * B_ * H_ * S_) / 4, 256, 0, stream>>>(Qb, Kb);

    attn_kernel<<<dim3(S_ / 64, B_ * H_), 256, 0, stream>>>(Qb, Kb, Vb, Ctxh);

    gemm_bf16_kernel<0><<<dim3(M_ / 128, D_ / 128, 1), 256, 0, stream>>>(
        Ctxh, Woh, b_o, b_o, b_o, out);
}

// Round 4
// 600.080 us; speedup vs baseline: 3.6191x; 1.0011x over previous
//
#include <hip/hip_runtime.h>
#include <hip/hip_bf16.h>
#include <math.h>

#define B_  4
#define S_  2048
#define D_  1024
#define H_  16
#define DK_ 64
#define M_  (B_ * S_)   // 8192 rows

typedef short short8 __attribute__((ext_vector_type(8)));
typedef float floatx4 __attribute__((ext_vector_type(4)));

__device__ inline unsigned short f2bf(float x) {
    unsigned u = __float_as_uint(x);
    u = (u + 0x7fff + ((u >> 16) & 1)) >> 16;   // round-to-nearest-even
    return (unsigned short)u;
}
__device__ inline float bf2f(unsigned short h) {
    return __uint_as_float(((unsigned)h) << 16);
}

#define GLOAD_LDS16(g, l)                                          \
    __builtin_amdgcn_global_load_lds(                              \
        (const __attribute__((address_space(1))) void*)(g),        \
        (__attribute__((address_space(3))) void*)(l), 16, 0, 0)

// ---------------------------------------------------------------------------
// fp32 -> bf16 converters
// ---------------------------------------------------------------------------
__global__ __launch_bounds__(256) void cvt_inputs_kernel(
    const float* __restrict__ q, const float* __restrict__ k,
    const float* __restrict__ v, unsigned short* __restrict__ Ah)
{
    const int z = blockIdx.z;
    const float* src = (z == 0) ? q : (z == 1) ? k : v;
    unsigned short* dst = Ah + (size_t)z * M_ * D_;
    const size_t i = ((size_t)blockIdx.x * 256 + threadIdx.x) * 4;
    float4 f = *(const float4*)(src + i);
    ushort4 o;
    o.x = f2bf(f.x); o.y = f2bf(f.y); o.z = f2bf(f.z); o.w = f2bf(f.w);
    *(ushort4*)(dst + i) = o;
}

__global__ __launch_bounds__(256) void cvt_weights_kernel(
    const float* __restrict__ wq, const float* __restrict__ wk,
    const float* __restrict__ wv, const float* __restrict__ wo,
    unsigned short* __restrict__ Wh, unsigned short* __restrict__ Woh)
{
    const int z = blockIdx.z;
    const float* src = (z == 0) ? wq : (z == 1) ? wk : (z == 2) ? wv : wo;
    unsigned short* dst = (z < 3) ? (Wh + (size_t)z * D_ * D_) : Woh;
    const size_t i = ((size_t)blockIdx.x * 256 + threadIdx.x) * 4;
    float4 f = *(const float4*)(src + i);
    ushort4 o;
    o.x = f2bf(f.x); o.y = f2bf(f.y); o.z = f2bf(f.z); o.w = f2bf(f.w);
    *(ushort4*)(dst + i) = o;
}

// ---------------------------------------------------------------------------
// bf16 MFMA NT-GEMM (m97 structure): C = A @ W^T + bias.
// MODE 0: fp32 row-major out (O-proj).
// MODE 1: bf16 scatter; z=0/1 (Q/K) -> [B,H,S,DK]; z=2 (V) -> [B,H,DK,S] (V^T).
// ---------------------------------------------------------------------------
template <int MODE>
__global__ __launch_bounds__(256) void gemm_bf16_kernel(
    const unsigned short* __restrict__ Ah, const unsigned short* __restrict__ Wh,
    const float* __restrict__ bq, const float* __restrict__ bk,
    const float* __restrict__ bv, void* __restrict__ outv)
{
    __shared__ __align__(16) unsigned short As[128 * 32];   // [m][k]
    __shared__ __align__(16) unsigned short Bs[128 * 32];   // [n][k]

    const int tid  = threadIdx.x;
    const int wave = tid >> 6;
    const int lane = tid & 63;
    const int quad = lane >> 4;
    const int l15  = lane & 15;
    const int z    = (MODE == 1) ? blockIdx.z : 0;
    const int m0   = blockIdx.x * 128;
    const int n0   = blockIdx.y * 128;
    const int wrow = (wave >> 1) * 64;
    const int wcol = (wave & 1) * 64;

    const unsigned short* A = Ah + (size_t)z * M_ * D_;
    const unsigned short* W = Wh + (size_t)z * D_ * D_;

    const int srow   = tid >> 2;
    const int schunk = (tid & 3) * 8;

    floatx4 acc[4][4] = {};

    for (int k0 = 0; k0 < D_; k0 += 32) {
        __syncthreads();
#pragma unroll
        for (int p = 0; p < 2; ++p) {
            const unsigned short* ga =
                A + (size_t)(m0 + p * 64 + srow) * D_ + k0 + schunk;
            GLOAD_LDS16(ga, &As[p * 2048 + wave * 512]);
            const unsigned short* gb =
                W + (size_t)(n0 + p * 64 + srow) * D_ + k0 + schunk;
            GLOAD_LDS16(gb, &Bs[p * 2048 + wave * 512]);
        }
        __syncthreads();

        short8 af[4], bf[4];
#pragma unroll
        for (int i = 0; i < 4; ++i)
            af[i] = *(const short8*)&As[(wrow + i * 16 + l15) * 32 + quad * 8];
#pragma unroll
        for (int j = 0; j < 4; ++j)
            bf[j] = *(const short8*)&Bs[(wcol + j * 16 + l15) * 32 + quad * 8];
#pragma unroll
        for (int i = 0; i < 4; ++i)
#pragma unroll
            for (int j = 0; j < 4; ++j)
                acc[i][j] = __builtin_amdgcn_mfma_f32_16x16x32_bf16(
                    af[i], bf[j], acc[i][j], 0, 0, 0);
    }

    const float* bias = (MODE == 0) ? bq : (z == 0) ? bq : (z == 1) ? bk : bv;

#pragma unroll
    for (int j = 0; j < 4; ++j) {
        const int n = n0 + wcol + j * 16 + l15;
        const float bn = bias[n];
#pragma unroll
        for (int i = 0; i < 4; ++i) {
#pragma unroll
            for (int reg = 0; reg < 4; ++reg) {
                const int m = m0 + wrow + i * 16 + quad * 4 + reg;
                const float v = acc[i][j][reg] + bn;
                if (MODE == 0) {
                    ((float*)outv)[(size_t)m * D_ + n] = v;
                } else {
                    const int b = m >> 11;
                    const int s = m & (S_ - 1);
                    const int h = n >> 6;
                    const int d = n & 63;
                    unsigned short* dst =
                        (unsigned short*)outv + (size_t)z * M_ * D_;
                    if (z < 2)
                        dst[(((size_t)b * H_ + h) * S_ + s) * DK_ + d] = f2bf(v);
                    else   // V stored transposed: [B,H,DK,S]
                        dst[(((size_t)b * H_ + h) * DK_ + d) * S_ + s] = f2bf(v);
                }
            }
        }
    }
}

// ---------------------------------------------------------------------------
// RoPE in-place on bf16 Q and K ([B*H, S, DK] compact). One wave per row.
// ---------------------------------------------------------------------------
__global__ __launch_bounds__(256) void rope_kernel(unsigned short* __restrict__ Q,
                                                   unsigned short* __restrict__ K)
{
    const int wave = blockIdx.x * 4 + (threadIdx.x >> 6);
    const int lane = threadIdx.x & 63;
    const int rowsPer = B_ * H_ * S_;

    unsigned short* base = (wave < rowsPer) ? Q : K;
    const int row = (wave < rowsPer) ? wave : wave - rowsPer;
    const int s = row & (S_ - 1);

    unsigned short* p = base + (size_t)row * DK_;
    const float v = bf2f(p[lane]);

    const int j = lane & 31;
    const float inv_freq = 1.0f / powf(10000.0f, (float)(2 * j) / (float)DK_);
    const float ang = (float)s * inv_freq;
    const float c  = cosf(ang);
    const float si = sinf(ang);

    const int partner = (lane < 32) ? (2 * lane + 1) : (2 * (lane - 32));
    const float sign = (lane < 32) ? -1.0f : 1.0f;
    const float pv = __shfl(v, partner);

    p[lane] = f2bf(v * c + sign * pv * si);
}

// ---------------------------------------------------------------------------
// Barrier-free MFMA flash attention.
// Block = 4 waves; each wave owns 16 Q rows of a 64-row q-tile. Each block
// processes the q-tile PAIR (x, 31-x) -> uniform 33 tile-iters/block.
// K,V fragments read DIRECTLY from global (V pre-transposed [B,H,DK,S]).
// Only P round-trips through per-wave LDS. No __syncthreads anywhere.
// ---------------------------------------------------------------------------
#define KSTR 72

__global__ __launch_bounds__(256) void attn_kernel(
    const unsigned short* __restrict__ Qh, const unsigned short* __restrict__ Kh,
    const unsigned short* __restrict__ Vt, unsigned short* __restrict__ ctx)
{
    __shared__ __align__(16) short Pw[4][16 * KSTR];   // per-wave P strip

    const int tid  = threadIdx.x;
    const int wave = tid >> 6;
    const int lane = tid & 63;
    const int quad = lane >> 4;
    const int l15  = lane & 15;
    const int bh   = blockIdx.y;
    const float scale = 0.125f;

    const unsigned short* Kbase = Kh + (size_t)bh * S_ * DK_;
    const unsigned short* Vbase = Vt + (size_t)bh * DK_ * S_;
    const int b = bh >> 4, h = bh & 15;

    short* Pme = &Pw[wave][0];

#pragma unroll
    for (int half = 0; half < 2; ++half) {
        const int qt = half ? (31 - blockIdx.x) : blockIdx.x;
        const int q0 = qt * 64;

        // Q A-fragments for this wave's 16 rows
        const unsigned short* Qrow =
            Qh + ((size_t)bh * S_ + q0 + wave * 16 + l15) * DK_;
        short8 aQ[2];
        aQ[0] = *(const short8*)(Qrow + quad * 8);
        aQ[1] = *(const short8*)(Qrow + 32 + quad * 8);

        floatx4 acc[4] = {};
        float m_i[4] = {-INFINITY, -INFINITY, -INFINITY, -INFINITY};
        float l_i[4] = {0.f, 0.f, 0.f, 0.f};

        for (int j0 = 0; j0 <= q0; j0 += 64) {
            // ---- scores: K B-frags straight from global ----
            floatx4 st[4] = {};
#pragma unroll
            for (int t = 0; t < 4; ++t) {
#pragma unroll
                for (int kh = 0; kh < 2; ++kh) {
                    short8 bK = *(const short8*)(
                        Kbase + (size_t)(j0 + t * 16 + l15) * DK_ +
                        kh * 32 + quad * 8);
                    st[t] = __builtin_amdgcn_mfma_f32_16x16x32_bf16(
                        aQ[kh], bK, st[t], 0, 0, 0);
                }
            }

            // ---- online softmax ----
            const bool diag = (j0 == q0);
            float s[4][4];
#pragma unroll
            for (int t = 0; t < 4; ++t)
#pragma unroll
                for (int reg = 0; reg < 4; ++reg) {
                    float v = st[t][reg] * scale;
                    if (diag && (t * 16 + l15 > wave * 16 + quad * 4 + reg))
                        v = -INFINITY;
                    s[t][reg] = v;
                }

#pragma unroll
            for (int reg = 0; reg < 4; ++reg) {
                float rmax = fmaxf(fmaxf(s[0][reg], s[1][reg]),
                                   fmaxf(s[2][reg], s[3][reg]));
                rmax = fmaxf(rmax, __shfl_xor(rmax, 1));
                rmax = fmaxf(rmax, __shfl_xor(rmax, 2));
                rmax = fmaxf(rmax, __shfl_xor(rmax, 4));
                rmax = fmaxf(rmax, __shfl_xor(rmax, 8));

                const float mn = fmaxf(m_i[reg], rmax);
                const float alpha = __expf(m_i[reg] - mn);
                float rs = 0.f;
#pragma unroll
                for (int t = 0; t < 4; ++t) {
                    const unsigned short pb = f2bf(__expf(s[t][reg] - mn));
                    Pme[(quad * 4 + reg) * KSTR + t * 16 + l15] = pb;
                    rs += bf2f(pb);
                }
                rs += __shfl_xor(rs, 1);
                rs += __shfl_xor(rs, 2);
                rs += __shfl_xor(rs, 4);
                rs += __shfl_xor(rs, 8);

                l_i[reg] = l_i[reg] * alpha + rs;
                m_i[reg] = mn;
#pragma unroll
                for (int t = 0; t < 4; ++t) acc[t][reg] *= alpha;
            }

            // ---- PV: P A-frags from LDS, V B-frags from global (V^T) ----
#pragma unroll
            for (int kh = 0; kh < 2; ++kh) {
                short8 aP = *(const short8*)&Pme[l15 * KSTR + kh * 32 + quad * 8];
#pragma unroll
                for (int t = 0; t < 4; ++t) {
                    short8 bV = *(const short8*)(
                        Vbase + (size_t)(t * 16 + l15) * S_ + j0 +
                        kh * 32 + quad * 8);
                    acc[t] = __builtin_amdgcn_mfma_f32_16x16x32_bf16(
                        aP, bV, acc[t], 0, 0, 0);
                }
            }
        }

        // ---- epilogue ----
#pragma unroll
        for (int reg = 0; reg < 4; ++reg) {
            const float inv = 1.0f / l_i[reg];
            const int q = q0 + wave * 16 + quad * 4 + reg;
            unsigned short* orow = ctx + ((size_t)b * S_ + q) * D_ + h * DK_;
#pragma unroll
            for (int t = 0; t < 4; ++t)
                orow[t * 16 + l15] = f2bf(acc[t][reg] * inv);
        }
    }
}

// ---------------------------------------------------------------------------
extern "C" void kernel_launch(void* const* d_in, const int* in_sizes, int n_in,
                              void* d_out, int out_size, void* d_ws, size_t ws_size,
                              hipStream_t stream)
{
    const float* query = (const float*)d_in[0];
    const float* key   = (const float*)d_in[1];
    const float* value = (const float*)d_in[2];
    const float* w_q = (const float*)d_in[4];
    const float* b_q = (const float*)d_in[5];
    const float* w_k = (const float*)d_in[6];
    const float* b_k = (const float*)d_in[7];
    const float* w_v = (const float*)d_in[8];
    const float* b_v = (const float*)d_in[9];
    const float* w_o = (const float*)d_in[10];
    const float* b_o = (const float*)d_in[11];
    float* out = (float*)d_out;

    char* ws = (char*)d_ws;
    const size_t half = (size_t)M_ * D_ * sizeof(unsigned short);   // 16.78 MB
    unsigned short* Ah   = (unsigned short*)(ws);                    // [3][M,D] bf16
    unsigned short* Wh   = (unsigned short*)(ws + 3 * half);         // [3][D,D]
    unsigned short* Woh  = (unsigned short*)(ws + 3 * half + 3 * half / 8);
    unsigned short* QKVb = (unsigned short*)(ws + 3 * half + 4 * half / 8);
    unsigned short* Ctxh = (unsigned short*)(ws + 6 * half + 4 * half / 8);

    cvt_inputs_kernel<<<dim3(M_ * D_ / 1024, 1, 3), 256, 0, stream>>>(
        query, key, value, Ah);
    cvt_weights_kernel<<<dim3(D_ * D_ / 1024, 1, 4), 256, 0, stream>>>(
        w_q, w_k, w_v, w_o, Wh, Woh);

    gemm_bf16_kernel<1><<<dim3(M_ / 128, D_ / 128, 3), 256, 0, stream>>>(
        Ah, Wh, b_q, b_k, b_v, QKVb);

    unsigned short* Qb = QKVb;
    unsigned short* Kb = QKVb + (size_t)M_ * D_;
    unsigned short* Vb = QKVb + 2 * (size_t)M_ * D_;   // transposed [B,H,DK,S]

    rope_kernel<<<(2 * B_ * H_ * S_) / 4, 256, 0, stream>>>(Qb, Kb);

    attn_kernel<<<dim3(16, B_ * H_), 256, 0, stream>>>(Qb, Kb, Vb, Ctxh);

    gemm_bf16_kernel<0><<<dim3(M_ / 128, D_ / 128, 1), 256, 0, stream>>>(
        Ctxh, Woh, b_o, b_o, b_o, out);
}

// Round 5
// 586.965 us; speedup vs baseline: 3.6999x; 1.0223x over previous
//
#include <hip/hip_runtime.h>
#include <hip/hip_bf16.h>
#include <math.h>

#define B_  4
#define S_  2048
#define D_  1024
#define H_  16
#define DK_ 64
#define M_  (B_ * S_)   // 8192 rows

typedef short short8 __attribute__((ext_vector_type(8)));
typedef float floatx4 __attribute__((ext_vector_type(4)));

__device__ inline unsigned short f2bf(float x) {
    unsigned u = __float_as_uint(x);
    u = (u + 0x7fff + ((u >> 16) & 1)) >> 16;   // round-to-nearest-even
    return (unsigned short)u;
}
__device__ inline float bf2f(unsigned short h) {
    return __uint_as_float(((unsigned)h) << 16);
}

// DPP row rotate (within 16-lane row) — VALU-pipe cross-lane
template <int K>
__device__ inline float dpp_ror(float x) {
    return __uint_as_float((unsigned)__builtin_amdgcn_update_dpp(
        0, (int)__float_as_uint(x), 0x120 | K, 0xF, 0xF, true));
}
__device__ inline float rowmax16(float x) {
    x = fmaxf(x, dpp_ror<8>(x));
    x = fmaxf(x, dpp_ror<4>(x));
    x = fmaxf(x, dpp_ror<2>(x));
    x = fmaxf(x, dpp_ror<1>(x));
    return x;
}
__device__ inline float rowsum16(float x) {
    x += dpp_ror<8>(x);
    x += dpp_ror<4>(x);
    x += dpp_ror<2>(x);
    x += dpp_ror<1>(x);
    return x;
}

#define GLOAD_LDS16(g, l)                                          \
    __builtin_amdgcn_global_load_lds(                              \
        (const __attribute__((address_space(1))) void*)(g),        \
        (__attribute__((address_space(3))) void*)(l), 16, 0, 0)

// ---------------------------------------------------------------------------
// fp32 -> bf16 converters
// ---------------------------------------------------------------------------
__global__ __launch_bounds__(256) void cvt_inputs_kernel(
    const float* __restrict__ q, const float* __restrict__ k,
    const float* __restrict__ v, unsigned short* __restrict__ Ah)
{
    const int z = blockIdx.z;
    const float* src = (z == 0) ? q : (z == 1) ? k : v;
    unsigned short* dst = Ah + (size_t)z * M_ * D_;
    const size_t i = ((size_t)blockIdx.x * 256 + threadIdx.x) * 4;
    float4 f = *(const float4*)(src + i);
    ushort4 o;
    o.x = f2bf(f.x); o.y = f2bf(f.y); o.z = f2bf(f.z); o.w = f2bf(f.w);
    *(ushort4*)(dst + i) = o;
}

__global__ __launch_bounds__(256) void cvt_weights_kernel(
    const float* __restrict__ wq, const float* __restrict__ wk,
    const float* __restrict__ wv, const float* __restrict__ wo,
    unsigned short* __restrict__ Wh, unsigned short* __restrict__ Woh)
{
    const int z = blockIdx.z;
    const float* src = (z == 0) ? wq : (z == 1) ? wk : (z == 2) ? wv : wo;
    unsigned short* dst = (z < 3) ? (Wh + (size_t)z * D_ * D_) : Woh;
    const size_t i = ((size_t)blockIdx.x * 256 + threadIdx.x) * 4;
    float4 f = *(const float4*)(src + i);
    ushort4 o;
    o.x = f2bf(f.x); o.y = f2bf(f.y); o.z = f2bf(f.z); o.w = f2bf(f.w);
    *(ushort4*)(dst + i) = o;
}

// ---------------------------------------------------------------------------
// bf16 MFMA NT-GEMM: C = A @ W^T + bias.
// MODE 0: fp32 row-major out (O-proj).
// MODE 1: bf16 scatter; z=0/1 (Q/K) -> [B,H,S,DK]; z=2 (V) -> [B,H,DK,S] via
//         per-wave LDS transpose (16B coalesced stores).
// ---------------------------------------------------------------------------
template <int MODE>
__global__ __launch_bounds__(256) void gemm_bf16_kernel(
    const unsigned short* __restrict__ Ah, const unsigned short* __restrict__ Wh,
    const float* __restrict__ bq, const float* __restrict__ bk,
    const float* __restrict__ bv, void* __restrict__ outv)
{
    __shared__ __align__(16) unsigned short As[128 * 32];   // [m][k]
    __shared__ __align__(16) unsigned short Bs[128 * 32];   // [n][k]
    __shared__ __align__(16) unsigned short Ts[MODE == 1 ? 4 * 16 * 68 : 4];

    const int tid  = threadIdx.x;
    const int wave = tid >> 6;
    const int lane = tid & 63;
    const int quad = lane >> 4;
    const int l15  = lane & 15;
    const int z    = (MODE == 1) ? blockIdx.z : 0;
    const int m0   = blockIdx.x * 128;
    const int n0   = blockIdx.y * 128;
    const int wrow = (wave >> 1) * 64;
    const int wcol = (wave & 1) * 64;

    const unsigned short* A = Ah + (size_t)z * M_ * D_;
    const unsigned short* W = Wh + (size_t)z * D_ * D_;

    const int srow   = tid >> 2;
    const int schunk = (tid & 3) * 8;

    floatx4 acc[4][4] = {};

    for (int k0 = 0; k0 < D_; k0 += 32) {
        __syncthreads();
#pragma unroll
        for (int p = 0; p < 2; ++p) {
            const unsigned short* ga =
                A + (size_t)(m0 + p * 64 + srow) * D_ + k0 + schunk;
            GLOAD_LDS16(ga, &As[p * 2048 + wave * 512]);
            const unsigned short* gb =
                W + (size_t)(n0 + p * 64 + srow) * D_ + k0 + schunk;
            GLOAD_LDS16(gb, &Bs[p * 2048 + wave * 512]);
        }
        __syncthreads();

        short8 af[4], bf[4];
#pragma unroll
        for (int i = 0; i < 4; ++i)
            af[i] = *(const short8*)&As[(wrow + i * 16 + l15) * 32 + quad * 8];
#pragma unroll
        for (int j = 0; j < 4; ++j)
            bf[j] = *(const short8*)&Bs[(wcol + j * 16 + l15) * 32 + quad * 8];
#pragma unroll
        for (int i = 0; i < 4; ++i)
#pragma unroll
            for (int j = 0; j < 4; ++j)
                acc[i][j] = __builtin_amdgcn_mfma_f32_16x16x32_bf16(
                    af[i], bf[j], acc[i][j], 0, 0, 0);
    }

    const float* bias = (MODE == 0) ? bq : (z == 0) ? bq : (z == 1) ? bk : bv;

    if (MODE == 1 && z == 2) {
        // V^T epilogue: transpose 64m x 16n strips through per-wave LDS
        __syncthreads();   // main-loop LDS reads done (Ts aliases nothing, but
                           // keep waves roughly aligned before heavy DS use)
        unsigned short* Tw = &Ts[wave * 16 * 68];
        const int bgl = m0 >> 11;
        const int s0g = (m0 & (S_ - 1)) + wrow + quad * 16;
#pragma unroll
        for (int j = 0; j < 4; ++j) {
            const int n = n0 + wcol + j * 16 + l15;
            const float bn = bias[n];
#pragma unroll
            for (int i = 0; i < 4; ++i)
#pragma unroll
                for (int reg = 0; reg < 4; ++reg)
                    Tw[l15 * 68 + i * 16 + quad * 4 + reg] =
                        f2bf(acc[i][j][reg] + bn);
            // wave-local LDS: same-wave DS ops are in-order; compiler waits
            short8 r0 = *(const short8*)&Tw[l15 * 68 + quad * 16];
            short8 r1 = *(const short8*)&Tw[l15 * 68 + quad * 16 + 8];
            const int h = n >> 6, d = n & 63;
            unsigned short* dp = (unsigned short*)outv + 2 * (size_t)M_ * D_ +
                (((size_t)(bgl * H_ + h)) * DK_ + d) * S_ + s0g;
            *(short8*)(dp) = r0;
            *(short8*)(dp + 8) = r1;
        }
        return;
    }

#pragma unroll
    for (int j = 0; j < 4; ++j) {
        const int n = n0 + wcol + j * 16 + l15;
        const float bn = bias[n];
#pragma unroll
        for (int i = 0; i < 4; ++i) {
#pragma unroll
            for (int reg = 0; reg < 4; ++reg) {
                const int m = m0 + wrow + i * 16 + quad * 4 + reg;
                const float v = acc[i][j][reg] + bn;
                if (MODE == 0) {
                    ((float*)outv)[(size_t)m * D_ + n] = v;
                } else {
                    const int b = m >> 11;
                    const int s = m & (S_ - 1);
                    const int h = n >> 6;
                    const int d = n & 63;
                    unsigned short* dst =
                        (unsigned short*)outv + (size_t)z * M_ * D_;
                    dst[(((size_t)b * H_ + h) * S_ + s) * DK_ + d] = f2bf(v);
                }
            }
        }
    }
}

// ---------------------------------------------------------------------------
// RoPE in-place on bf16 Q and K ([B*H, S, DK] compact). One wave per row.
// ---------------------------------------------------------------------------
__global__ __launch_bounds__(256) void rope_kernel(unsigned short* __restrict__ Q,
                                                   unsigned short* __restrict__ K)
{
    const int wave = blockIdx.x * 4 + (threadIdx.x >> 6);
    const int lane = threadIdx.x & 63;
    const int rowsPer = B_ * H_ * S_;

    unsigned short* base = (wave < rowsPer) ? Q : K;
    const int row = (wave < rowsPer) ? wave : wave - rowsPer;
    const int s = row & (S_ - 1);

    unsigned short* p = base + (size_t)row * DK_;
    const float v = bf2f(p[lane]);

    const int j = lane & 31;
    const float inv_freq = 1.0f / powf(10000.0f, (float)(2 * j) / (float)DK_);
    const float ang = (float)s * inv_freq;
    const float c  = cosf(ang);
    const float si = sinf(ang);

    const int partner = (lane < 32) ? (2 * lane + 1) : (2 * (lane - 32));
    const float sign = (lane < 32) ? -1.0f : 1.0f;
    const float pv = __shfl(v, partner);

    p[lane] = f2bf(v * c + sign * pv * si);
}

// ---------------------------------------------------------------------------
// Barrier-free MFMA flash attention, software-pipelined + XCD-swizzled.
// Linear grid L=0..1023: xcd=L&7, bh=((L>>3)&7)*8+xcd, qpair=L>>6.
// All q-blocks of a head share an XCD -> K+V (8 heads x 512KB = 4MB) fit L2.
// K double-buffered in regs across tile-iters; V issued at iter top.
// Softmax in exp2 domain; DPP reductions (VALU pipe, not LDS).
// ---------------------------------------------------------------------------
#define KSTR 72

__global__ __launch_bounds__(256, 3) void attn_kernel(
    const unsigned short* __restrict__ Qh, const unsigned short* __restrict__ Kh,
    const unsigned short* __restrict__ Vt, unsigned short* __restrict__ ctx)
{
    __shared__ __align__(16) short Pw[4][16 * KSTR];   // per-wave P strip

    const int tid  = threadIdx.x;
    const int wave = tid >> 6;
    const int lane = tid & 63;
    const int quad = lane >> 4;
    const int l15  = lane & 15;

    const int L     = blockIdx.x;
    const int bh    = ((L >> 3) & 7) * 8 + (L & 7);
    const int qpair = L >> 6;

    const float c2 = 0.18033688011f;   // 0.125 * log2(e)

    const unsigned short* Kbase = Kh + (size_t)bh * S_ * DK_;
    const unsigned short* Vbase = Vt + (size_t)bh * DK_ * S_;
    const int b = bh >> 4, h = bh & 15;

    short* Pme = &Pw[wave][0];

#pragma unroll
    for (int half = 0; half < 2; ++half) {
        const int qt = half ? (31 - qpair) : qpair;
        const int q0 = qt * 64;

        const unsigned short* Qrow =
            Qh + ((size_t)bh * S_ + q0 + wave * 16 + l15) * DK_;
        short8 aQ[2];
        aQ[0] = *(const short8*)(Qrow + quad * 8);
        aQ[1] = *(const short8*)(Qrow + 32 + quad * 8);

        floatx4 acc[4] = {};
        float m_i[4] = {-INFINITY, -INFINITY, -INFINITY, -INFINITY};
        float l_i[4] = {0.f, 0.f, 0.f, 0.f};

        // prime K register double-buffer for j0 = 0
        short8 curK[8];
#pragma unroll
        for (int t = 0; t < 4; ++t)
#pragma unroll
            for (int kh = 0; kh < 2; ++kh)
                curK[t * 2 + kh] = *(const short8*)(
                    Kbase + (size_t)(t * 16 + l15) * DK_ + kh * 32 + quad * 8);

        for (int j0 = 0; j0 <= q0; j0 += 64) {
            // V fragments for this tile (independent -> issued early)
            short8 curV[8];
#pragma unroll
            for (int t = 0; t < 4; ++t)
#pragma unroll
                for (int kh = 0; kh < 2; ++kh)
                    curV[t * 2 + kh] = *(const short8*)(
                        Vbase + (size_t)(t * 16 + l15) * S_ + j0 +
                        kh * 32 + quad * 8);

            // QK^T from register-resident K
            floatx4 st[4] = {};
#pragma unroll
            for (int t = 0; t < 4; ++t)
#pragma unroll
                for (int kh = 0; kh < 2; ++kh)
                    st[t] = __builtin_amdgcn_mfma_f32_16x16x32_bf16(
                        aQ[kh], curK[t * 2 + kh], st[t], 0, 0, 0);

            // prefetch next tile's K (latency covered by softmax + PV)
            const int jn = (j0 + 64 <= q0) ? j0 + 64 : j0;
            short8 nxtK[8];
#pragma unroll
            for (int t = 0; t < 4; ++t)
#pragma unroll
                for (int kh = 0; kh < 2; ++kh)
                    nxtK[t * 2 + kh] = *(const short8*)(
                        Kbase + (size_t)(jn + t * 16 + l15) * DK_ +
                        kh * 32 + quad * 8);

            // causal mask (diag tile only; wave-uniform branch)
            if (j0 == q0) {
#pragma unroll
                for (int t = 0; t < 4; ++t)
#pragma unroll
                    for (int reg = 0; reg < 4; ++reg)
                        if (t * 16 + l15 > wave * 16 + quad * 4 + reg)
                            st[t][reg] = -INFINITY;
            }

            // online softmax, exp2 domain
#pragma unroll
            for (int reg = 0; reg < 4; ++reg) {
                float rmx = fmaxf(fmaxf(st[0][reg], st[1][reg]),
                                  fmaxf(st[2][reg], st[3][reg]));
                rmx = rowmax16(rmx);
                const float m2 = fmaxf(m_i[reg], rmx * c2);
                const float alpha = exp2f(m_i[reg] - m2);
                float rs = 0.f;
#pragma unroll
                for (int t = 0; t < 4; ++t) {
                    const float p = exp2f(fmaf(st[t][reg], c2, -m2));
                    Pme[(quad * 4 + reg) * KSTR + t * 16 + l15] = f2bf(p);
                    rs += p;
                }
                rs = rowsum16(rs);
                l_i[reg] = l_i[reg] * alpha + rs;
                m_i[reg] = m2;
                if (__ballot(alpha == 1.0f) != ~0ull) {
#pragma unroll
                    for (int t = 0; t < 4; ++t) acc[t][reg] *= alpha;
                }
            }

            // PV: P A-frags from per-wave LDS, V from registers
#pragma unroll
            for (int kh = 0; kh < 2; ++kh) {
                short8 aP = *(const short8*)&Pme[l15 * KSTR + kh * 32 + quad * 8];
#pragma unroll
                for (int t = 0; t < 4; ++t)
                    acc[t] = __builtin_amdgcn_mfma_f32_16x16x32_bf16(
                        aP, curV[t * 2 + kh], acc[t], 0, 0, 0);
            }

            // rotate K buffers
#pragma unroll
            for (int i = 0; i < 8; ++i) curK[i] = nxtK[i];
        }

        // epilogue
#pragma unroll
        for (int reg = 0; reg < 4; ++reg) {
            const float inv = 1.0f / l_i[reg];
            const int q = q0 + wave * 16 + quad * 4 + reg;
            unsigned short* orow = ctx + ((size_t)b * S_ + q) * D_ + h * DK_;
#pragma unroll
            for (int t = 0; t < 4; ++t)
                orow[t * 16 + l15] = f2bf(acc[t][reg] * inv);
        }
    }
}

// ---------------------------------------------------------------------------
extern "C" void kernel_launch(void* const* d_in, const int* in_sizes, int n_in,
                              void* d_out, int out_size, void* d_ws, size_t ws_size,
                              hipStream_t stream)
{
    const float* query = (const float*)d_in[0];
    const float* key   = (const float*)d_in[1];
    const float* value = (const float*)d_in[2];
    const float* w_q = (const float*)d_in[4];
    const float* b_q = (const float*)d_in[5];
    const float* w_k = (const float*)d_in[6];
    const float* b_k = (const float*)d_in[7];
    const float* w_v = (const float*)d_in[8];
    const float* b_v = (const float*)d_in[9];
    const float* w_o = (const float*)d_in[10];
    const float* b_o = (const float*)d_in[11];
    float* out = (float*)d_out;

    char* ws = (char*)d_ws;
    const size_t half = (size_t)M_ * D_ * sizeof(unsigned short);   // 16.78 MB
    unsigned short* Ah   = (unsigned short*)(ws);                    // [3][M,D] bf16
    unsigned short* Wh   = (unsigned short*)(ws + 3 * half);         // [3][D,D]
    unsigned short* Woh  = (unsigned short*)(ws + 3 * half + 3 * half / 8);
    unsigned short* QKVb = (unsigned short*)(ws + 3 * half + 4 * half / 8);
    unsigned short* Ctxh = (unsigned short*)(ws + 6 * half + 4 * half / 8);

    cvt_inputs_kernel<<<dim3(M_ * D_ / 1024, 1, 3), 256, 0, stream>>>(
        query, key, value, Ah);
    cvt_weights_kernel<<<dim3(D_ * D_ / 1024, 1, 4), 256, 0, stream>>>(
        w_q, w_k, w_v, w_o, Wh, Woh);

    gemm_bf16_kernel<1><<<dim3(M_ / 128, D_ / 128, 3), 256, 0, stream>>>(
        Ah, Wh, b_q, b_k, b_v, QKVb);

    unsigned short* Qb = QKVb;
    unsigned short* Kb = QKVb + (size_t)M_ * D_;
    unsigned short* Vb = QKVb + 2 * (size_t)M_ * D_;   // transposed [B,H,DK,S]

    rope_kernel<<<(2 * B_ * H_ * S_) / 4, 256, 0, stream>>>(Qb, Kb);

    attn_kernel<<<dim3(1024), 256, 0, stream>>>(Qb, Kb, Vb, Ctxh);

    gemm_bf16_kernel<0><<<dim3(M_ / 128, D_ / 128, 1), 256, 0, stream>>>(
        Ctxh, Woh, b_o, b_o, b_o, out);
}